// Round 8
// baseline (342.165 us; speedup 1.0000x reference)
//
#include <hip/hip_runtime.h>
#include <cstdint>
#include <cstddef>

#define N_DIM 4096
#define M_DIM 4096
#define D_DIM 4096

typedef unsigned short u16;
typedef short s16x8 __attribute__((ext_vector_type(8)));   // 8 bf16 (4 VGPRs)
typedef float f32x4 __attribute__((ext_vector_type(4)));   // MFMA accumulator

// 8 f32 -> 8 bf16 (RNE), 4 instructions. cvt_pk has no builtin on gfx950;
// inline asm per T12 recipe (refcheck precedent: learn_hip m214v22).
__device__ __forceinline__ s16x8 cvt8(f32x4 a, f32x4 b) {
    union { s16x8 v; uint32_t w[4]; } r;
    asm("v_cvt_pk_bf16_f32 %0, %1, %2" : "=v"(r.w[0]) : "v"(a[0]), "v"(a[1]));
    asm("v_cvt_pk_bf16_f32 %0, %1, %2" : "=v"(r.w[1]) : "v"(a[2]), "v"(a[3]));
    asm("v_cvt_pk_bf16_f32 %0, %1, %2" : "=v"(r.w[2]) : "v"(b[0]), "v"(b[1]));
    asm("v_cvt_pk_bf16_f32 %0, %1, %2" : "=v"(r.w[3]) : "v"(b[2]), "v"(b[3]));
    return r.v;
}

// ---- LDS geometry (identical to r2-r7, verified 0 bank conflicts) ----
// 8 regions of 16 KB: {A,B} x {buf0,buf1} x {khalf0,khalf1}; region =
// 256 rows x 32 bf16. Row = 64 B = 4 chunks of 16 B; logical chunk c of
// row r stored at physical chunk c ^ ((r>>1)&3). Staging is now
// reg-staged (global f32 -> cvt -> swizzled ds_write_b128), which lets us
// write the swizzled address directly (no inverse-on-source trick needed).
__device__ __forceinline__ int frag_off(int row, int cbq) {
    return row * 32 + (cbq ^ ((row >> 1) & 3)) * 8;
}

// Issue 4x dwordx4 f32 loads (2 slots x 8 floats) for one region, K-offset
// K (f32 cols). Consumed by WRITER 2 phases later (~2300 cyc > HBM 900).
#define LOADR(R, G, K)                                                        \
    R[0] = *(const f32x4*)((G) + l0f + (K));                                  \
    R[1] = *(const f32x4*)((G) + l0f + (K) + 4);                              \
    R[2] = *(const f32x4*)((G) + l1f + (K));                                  \
    R[3] = *(const f32x4*)((G) + l1f + (K) + 4);

// Convert + swizzled LDS write of one region share (2x ds_write_b128).
// Compiler inserts the precise vmcnt wait on R before each write (r5
// lesson: keep register global-loads OUT of any manual-vmcnt discipline —
// here there IS no manual vmcnt left anywhere in the loop).
#define WRITER(R, L)                                                          \
    *(s16x8*)&(L)[wr0] = cvt8(R[0], R[1]);                                    \
    *(s16x8*)&(L)[wr1] = cvt8(R[2], R[3]);

// Phase (r7 skeleton minus all manual vmcnt): 4 A ds_reads (+4 B on MH==0),
// stage writes/loads for future phases, barrier, lgkmcnt(0) (drains this
// phase's frag reads AND this wave's ds_writes -> regions written at phase p
// are globally visible after p's end barrier), setprio-wrapped 16 MFMA,
// barrier.
// RAW: every region is written >=5 phases before first read.
// WAR: write-slot schedule identical to r7 (re-write 1 drained-barrier
// after last read).
#define PHASE(AR, BR, MH, ...)                                                \
  {                                                                           \
    s16x8 af[4];                                                              \
    _Pragma("unroll")                                                         \
    for (int i = 0; i < 4; ++i)                                               \
      af[i] = *(const s16x8*)&(AR)[(MH) ? aoff1[i] : aoff0[i]];               \
    if (!(MH)) {                                                              \
      _Pragma("unroll")                                                       \
      for (int q = 0; q < 4; ++q)                                             \
        bfp[q] = *(const s16x8*)&(BR)[boff[q]];                               \
    }                                                                         \
    __VA_ARGS__                                                               \
    __builtin_amdgcn_s_barrier();                                             \
    asm volatile("s_waitcnt lgkmcnt(0)");                                     \
    __builtin_amdgcn_s_setprio(1);                                            \
    _Pragma("unroll")                                                         \
    for (int i = 0; i < 4; ++i) {                                             \
      _Pragma("unroll")                                                       \
      for (int q = 0; q < 4; ++q)                                             \
        acc[(MH) * 4 + i][q] = __builtin_amdgcn_mfma_f32_16x16x32_bf16(       \
            af[i], bfp[q], acc[(MH) * 4 + i][q], 0, 0, 0);                    \
    }                                                                         \
    __builtin_amdgcn_s_setprio(0);                                            \
    __builtin_amdgcn_s_barrier();                                             \
  }

// 256x256 macro-tile, BK=64, 8 phases / 2 K-tiles, 512 threads, fp32 inputs
// converted in-staging (convert kernel eliminated).
// Per-iteration slot schedule (load @p-2 -> write @p -> first read @p+5..6):
//   P0: wr sA11,sB11 (<-prev P6 loads)   ld rA00 <-A(t+2)k0
//   P1:                                  ld rB00 <-B(t+2)k0
//   P2: wr sA00                          ld rA01,rB01 <-(t+2)k1
//   P3: wr sB00
//   P4: wr sA01,sB01                     ld rA10 <-A(t+3)k0
//   P5:                                  ld rB10 <-B(t+3)k0
//   P6: wr sA10                          ld rA11,rB11 <-(t+3)k1
//   P7: wr sB10
// Peak staging liveness = 3 regions = 48 VGPR.
__global__ __launch_bounds__(512) void gemm_fused(
    const float* __restrict__ A, const float* __restrict__ B, float* __restrict__ C) {
    __shared__ __align__(16) u16 sm[65536];            // 128 KB
    u16* sA00 = sm;          u16* sA01 = sm + 8192;
    u16* sA10 = sm + 16384;  u16* sA11 = sm + 24576;
    u16* sB00 = sm + 32768;  u16* sB01 = sm + 40960;
    u16* sB10 = sm + 49152;  u16* sB11 = sm + 57344;

    const int tid   = threadIdx.x;
    const int lane  = tid & 63;
    const int wave  = tid >> 6;       // 0..7
    const int waveM = wave >> 2;      // 0..1
    const int waveN = wave & 3;       // 0..3
    const int fr    = lane & 15;
    const int cbq   = lane >> 4;

    // XCD-compact swizzle: 256 blocks, 16x16 tile grid (as r0-r7).
    const int lin  = blockIdx.x;
    const int xcd  = lin & 7;
    const int j    = lin >> 3;
    const int tileY = (xcd >> 1) * 4 + (j & 3);
    const int tileX = (xcd & 1) * 8 + (j >> 2);
    const int rowBase = tileY * 256;
    const int colBase = tileX * 256;

    const float* A32b = A + (size_t)rowBase * D_DIM;
    const float* B32b = B + (size_t)colBase * D_DIM;

    // Staging slots (2/thread/region): slot s -> row r=s>>2, logical chunk
    // c=s&3. Global f32 source: r*D + c*8 (+K). Swizzled LDS dest (u16):
    // r*32 + (c^((r>>1)&3))*8.
    const int s0 = wave * 64 + lane;
    const int s1 = 512 + wave * 64 + lane;
    const int r0 = s0 >> 2, c0 = s0 & 3;
    const int r1 = s1 >> 2, c1 = s1 & 3;
    const size_t l0f = (size_t)r0 * D_DIM + (size_t)(c0 * 8);
    const size_t l1f = (size_t)r1 * D_DIM + (size_t)(c1 * 8);
    const int wr0 = r0 * 32 + ((c0 ^ ((r0 >> 1) & 3)) * 8);
    const int wr1 = r1 * 32 + ((c1 ^ ((r1 >> 1) & 3)) * 8);

    // Fragment read offsets (u16 units)
    int aoff0[4], aoff1[4], boff[4];
    #pragma unroll
    for (int i = 0; i < 4; ++i) {
        aoff0[i] = frag_off(waveM * 128 + i * 16 + fr, cbq);
        aoff1[i] = frag_off(waveM * 128 + 64 + i * 16 + fr, cbq);
        boff[i]  = frag_off(waveN * 64 + i * 16 + fr, cbq);
    }

    f32x4 acc[8][4] = {};
    s16x8 bfp[4];
    f32x4 rA00[4], rB00[4], rA01[4], rB01[4], rA10[4], rB10[4], rA11[4], rB11[4];

    // Prologue: fill t0(k0,k1), t1(k0) directly; pre-issue t1k1 loads
    // (written at P0 of iteration 0).
    LOADR(rA00, A32b, 0)   LOADR(rB00, B32b, 0)
    LOADR(rA01, A32b, 32)  LOADR(rB01, B32b, 32)
    LOADR(rA10, A32b, 64)  LOADR(rB10, B32b, 64)
    WRITER(rA00, sA00)  WRITER(rB00, sB00)
    WRITER(rA01, sA01)  WRITER(rB01, sB01)
    WRITER(rA10, sA10)  WRITER(rB10, sB10)
    LOADR(rA11, A32b, 96)  LOADR(rB11, B32b, 96)
    asm volatile("s_waitcnt lgkmcnt(0)");
    __builtin_amdgcn_s_barrier();

    // Tail clamps load/write dead (valid-address) data into regions never
    // read again; keeps per-phase op counts uniform.
    #pragma unroll 1
    for (int t = 0; t < 64; t += 2) {
        const size_t k2 = (size_t)((t + 2 < 64) ? t + 2 : 63) * 64;
        const size_t k3 = (size_t)((t + 3 < 64) ? t + 3 : 63) * 64;

        PHASE(sA00, sB00, 0, WRITER(rA11, sA11) WRITER(rB11, sB11)
                             LOADR(rA00, A32b, k2))                       // P0
        PHASE(sA00, sB00, 1, LOADR(rB00, B32b, k2))                       // P1
        PHASE(sA01, sB01, 0, WRITER(rA00, sA00)
                             LOADR(rA01, A32b, k2 + 32)
                             LOADR(rB01, B32b, k2 + 32))                  // P2
        PHASE(sA01, sB01, 1, WRITER(rB00, sB00))                          // P3
        PHASE(sA10, sB10, 0, WRITER(rA01, sA01) WRITER(rB01, sB01)
                             LOADR(rA10, A32b, k3))                       // P4
        PHASE(sA10, sB10, 1, LOADR(rB10, B32b, k3))                       // P5
        PHASE(sA11, sB11, 0, WRITER(rA10, sA10)
                             LOADR(rA11, A32b, k3 + 32)
                             LOADR(rB11, B32b, k3 + 32))                  // P6
        PHASE(sA11, sB11, 1, WRITER(rB10, sB10))                          // P7
    }

    // Epilogue. C/D layout (verified m89/m91): col = lane&15, row = (lane>>4)*4 + reg
    #pragma unroll
    for (int mt = 0; mt < 8; ++mt) {
        int gr0 = rowBase + waveM * 128 + mt * 16 + (lane >> 4) * 4;
        #pragma unroll
        for (int nt = 0; nt < 4; ++nt) {
            int gc = colBase + waveN * 64 + nt * 16 + (lane & 15);
            #pragma unroll
            for (int r = 0; r < 4; ++r)
                C[(size_t)(gr0 + r) * M_DIM + gc] = acc[mt][nt][r];
        }
    }
}

extern "C" void kernel_launch(void* const* d_in, const int* in_sizes, int n_in,
                              void* d_out, int out_size, void* d_ws, size_t ws_size,
                              hipStream_t stream) {
    const float* A32 = (const float*)d_in[0];
    const float* B32 = (const float*)d_in[1];
    float* C = (float*)d_out;
    gemm_fused<<<256, 512, 0, stream>>>(A32, B32, C);
}